// Round 11
// baseline (89.745 us; speedup 1.0000x reference)
//
#include <hip/hip_runtime.h>
#include <math.h>

// Contour-to-distance-map, round 11.
// 10-round synthesis: chain-steps/SIMD is always 450; wall/chain-step floors
// at ~170cy regardless of body weight (28-100cy), occupancy (2.25-9 waves),
// ILP (1-4 chains), branching. The never-varied invariant: one LDS/SMEM
// access per chain-step for the vertex. Theory: per-CU scalar/LDS service
// (SMEM returns out-of-order -> conservative lgkmcnt; serialized per CU) is
// the ~170cy quantum. Fix: ZERO in-loop memory ops — the padded contour
// (256 x 8B = 2KB) lives in 8 VGPRs/lane (lane L holds vertices 4L..4L+3);
// step n=4g+r fetches via 2x v_readlane (g uniform SGPR, r compile-time).
// One wave = all 200 edges x its 64 pixels; steps n=0 / n>200 are exact
// no-ops (c0->c0: crz==0, dot>0). R8's guarded-exact correction per group.

#define INV_2PI 0.15915494309189535f
#define TWO_PI  6.28318530717958648f
#define PI_F    3.14159265358979323846f
#define HPI_F   1.57079632679489662f
#define KK2     200000.0f             // 2*k
#define CTHR    9e-5f                 // |crz| below this -> exact correction

__device__ __forceinline__ float atan01(float q) {
    // A&S 4.4.49: atan(q), q in [0,1], |err| <= 1e-5
    const float z = q * q;
    float p = fmaf(z,  0.0208351f, -0.0851330f);
    p = fmaf(z, p,  0.1801410f);
    p = fmaf(z, p, -0.3302995f);
    p = fmaf(z, p,  0.9998660f);
    return q * p;
}

__global__ void prep_kernel(const float2* __restrict__ contour,
                            float2* __restrict__ ext, int N) {
    const int t = threadIdx.x;               // one block of 256
    ext[t] = contour[(t < N) ? t : 0];
}

__device__ __forceinline__ float rdlane(int vreg, int g) {
    return __int_as_float(__builtin_amdgcn_readlane(vreg, g));
}

__global__ void __launch_bounds__(256, 4)
winding_kernel(const float2* __restrict__ ext, int S, float invS,
               float* __restrict__ out, float* __restrict__ bmax) {
    const int tid  = threadIdx.x;
    const int lane = tid & 63;
    const int wid  = tid >> 6;

    // ---- register-resident contour: lane L holds vertices 4L..4L+3 ----
    const float4* e4 = (const float4*)ext;
    const float4 va = e4[2 * lane];
    const float4 vb = e4[2 * lane + 1];
    int vxi[4], vyi[4];
    vxi[0] = __float_as_int(va.x); vyi[0] = __float_as_int(va.y);
    vxi[1] = __float_as_int(va.z); vyi[1] = __float_as_int(va.w);
    vxi[2] = __float_as_int(vb.x); vyi[2] = __float_as_int(vb.y);
    vxi[3] = __float_as_int(vb.z); vyi[3] = __float_as_int(vb.w);

    // this wave's 64 pixels (147456 = 576*256, no bounds checks)
    const int p = blockIdx.x * 256 + wid * 64 + lane;
    const int i = p / S, j = p - i * S;
    const float px = (float)i * invS, py = (float)j * invS;

    // init from vertex 0
    float dxp = rdlane(vxi[0], 0) - px;
    float dyp = rdlane(vyi[0], 0) - py;
    float minn  = fmaf(dxp, dxp, dyp * dyp);
    float wcorr = 0.0f;
    int   wind  = 0;

    // groups g=0..50 cover steps n=4g+r in [0,203]; n=0 and n in [201,203]
    // are exact no-ops (c0->c0 edges).
    for (int g = 0; g <= 50; ++g) {
        float dxa[5], dya[5], crza[4];
        dxa[0] = dxp; dya[0] = dyp;

        #pragma unroll
        for (int r = 0; r < 4; ++r) {
            const float vx = rdlane(vxi[r], g);     // 2 VALU, no memory
            const float vy = rdlane(vyi[r], g);
            const float dxn = vx - px;
            const float dyn = vy - py;
            dxa[r + 1] = dxn; dya[r + 1] = dyn;
            const float d2 = fmaf(dxn, dxn, dyn * dyn);
            minn = fminf(minn, d2);
            const float crz = fmaf(dxa[r], dyn, -(dya[r] * dxn));
            crza[r] = crz;
            // half-open ray crossing (same predicates as R8/R9/R10)
            const bool pc = (dya[r] <= 0.0f);
            const bool pn = (dyn    <= 0.0f);
            const int up = (pc & !pn & (crz > 0.0f)) ? 1 : 0;
            const int dn = (!pc & pn & (crz < 0.0f)) ? 1 : 0;
            wind += up - dn;
        }

        const float amin = fminf(fminf(fabsf(crza[0]), fabsf(crza[1])),
                                 fminf(fabsf(crza[2]), fabsf(crza[3])));
        if (__any(amin < CTHR)) {        // rare: exact tanh-weight correction
            #pragma unroll
            for (int r = 0; r < 4; ++r) {
                const float crz = crza[r];
                const float dot = fmaf(dxa[r], dxa[r + 1],
                                       dya[r] * dya[r + 1]);
                const float ay = fabsf(crz);
                const float ax = fabsf(dot);
                const float mn = fminf(ax, ay);
                const float mx = fmaxf(ax, ay);
                const float qq = mn * __builtin_amdgcn_rcpf(fmaxf(mx, 1e-30f));
                float an = atan01(qq);
                an = (ay > ax)    ? (HPI_F - an) : an;
                an = (dot < 0.0f) ? (PI_F - an)  : an;
                const float e = __expf(ay * -KK2);
                const float t = (1.0f - e) * __builtin_amdgcn_rcpf(1.0f + e);
                // (1-t)==0 exactly for |crz|>=CTHR -> no lane mask needed
                wcorr = fmaf(1.0f - t, copysignf(an, -crz), wcorr);
            }
        }
        dxp = dxa[4]; dyp = dya[4];
    }

    const float wt = fmaf(-TWO_PI, (float)wind, -wcorr);
    const float prod = (wt * INV_2PI) * __builtin_amdgcn_sqrtf(minn);
    out[p] = prod;

    // per-wave max -> bmax[block*4+wid]  (no __syncthreads anywhere)
    float v = prod;
    #pragma unroll
    for (int off = 32; off >= 1; off >>= 1)
        v = fmaxf(v, __shfl_down(v, off, 64));
    if (lane == 0) bmax[blockIdx.x * 4 + wid] = v;
}

__global__ void __launch_bounds__(256)
normalize_kernel(float4* __restrict__ out4, const float* __restrict__ bmax,
                 int nmax, int total4) {
    const int tid  = threadIdx.x;
    const int lane = tid & 63;
    const int wid  = tid >> 6;

    float m = -INFINITY;
    for (int t = tid; t < nmax; t += 256) m = fmaxf(m, bmax[t]);
    #pragma unroll
    for (int off = 32; off >= 1; off >>= 1)
        m = fmaxf(m, __shfl_down(m, off, 64));
    __shared__ float sm[4];
    if (lane == 0) sm[wid] = m;
    __syncthreads();
    m = fmaxf(fmaxf(sm[0], sm[1]), fmaxf(sm[2], sm[3]));
    const float inv = 1.0f / m;

    const int idx = blockIdx.x * 256 + tid;
    if (idx < total4) {
        float4 v = out4[idx];
        v.x *= inv; v.y *= inv; v.z *= inv; v.w *= inv;
        out4[idx] = v;
    }
}

extern "C" void kernel_launch(void* const* d_in, const int* in_sizes, int n_in,
                              void* d_out, int out_size, void* d_ws, size_t ws_size,
                              hipStream_t stream) {
    const float2* contour = (const float2*)d_in[0];
    const int N = in_sizes[0] / 2;                       // 200 (must be <=255)
    const int S = (int)(sqrt((double)out_size) + 0.5);   // 384
    const float invS = 1.0f / (float)S;
    float* out  = (float*)d_out;
    float* bmax = (float*)d_ws;                          // 2304 floats
    float2* ext = (float2*)((char*)d_ws + 16384);        // 256 padded vertices

    prep_kernel<<<1, 256, 0, stream>>>(contour, ext, N);

    const int total   = S * S;
    const int wblocks = total / 256;                     // 576 (exact)
    winding_kernel<<<wblocks, 256, 0, stream>>>(ext, S, invS, out, bmax);

    const int total4  = total / 4;
    const int nblocks = (total4 + 255) / 256;            // 144
    normalize_kernel<<<nblocks, 256, 0, stream>>>((float4*)out, bmax,
                                                  wblocks * 4, total4);
}

// Round 12
// 85.374 us; speedup vs baseline: 1.0512x; 1.0512x over previous
//
#include <hip/hip_runtime.h>
#include <math.h>

// Contour-to-distance-map, round 12.
// R11 killed the memory-pipe theory. Re-analysis of R10: its 224 cy/wave-step
// ~= its issue arithmetic (4x(14 VALU + exp+rcp) ~= 215 cy) -> at ILP-4 the
// per-wave-step constant is AMORTIZED and the kernel is issue-bound; R10 lost
// only because it made the correction branchless (2 transcendentals/chain-
// step). R12 = R10 skeleton + cheap guarded correction + algebraic op diet:
//   d2  = A - 2v.p + |p|^2   (|p|^2 added once in epilogue)
//   crz = C + py*EX - px*EY  (per-edge constants from a prep table)
// -> 12 VALU/chain-step, no carried dx. Expansion rounding == ~1.5e-7
// perturbation of p; gate and slow path consume the SAME crz so the
// wind/correction identity stays self-consistent (R8 argument).
// Guard: __any(min4|crz| < 9e-5) per step (~11% fire, +~26cy avg).

#define INV_2PI 0.15915494309189535f
#define TWO_PI  6.28318530717958648f
#define PI_F    3.14159265358979323846f
#define HPI_F   1.57079632679489662f
#define KK2     200000.0f             // 2*k
#define CTHR    9e-5f                 // |crz| below this -> exact correction

__device__ __forceinline__ float atan01(float q) {
    // A&S 4.4.49: atan(q), q in [0,1], |err| <= 1e-5
    const float z = q * q;
    float p = fmaf(z,  0.0208351f, -0.0851330f);
    p = fmaf(z, p,  0.1801410f);
    p = fmaf(z, p, -0.3302995f);
    p = fmaf(z, p,  0.9998660f);
    return q * p;
}

// Record u (u in [0,205)), 3 float4s:
//  q0 = {vy(u), -2vx(u), -2vy(u), A(u)=|v(u)|^2}   vertex part
//  q1 = {EX, -EY, C, vx(u)}        edge (u-1 -> u): EX=vx(u)-vx(u-1), C=cross
//  q2 = {vx(u-1), vy(u-1), 0, 0}   prev vertex (slow path only)
// vertex(u) = c[u<N?u:0] (padded polygon; pad edges are exact no-ops).
__global__ void prep_kernel(const float2* __restrict__ c,
                            float4* __restrict__ T, int N) {
    const int u = threadIdx.x;               // one block of 256
    if (u >= 205) return;
    const float2 v1 = c[(u < N) ? u : 0];
    const float2 v0 = (u == 0) ? v1 : c[((u - 1) < N) ? (u - 1) : 0];
    T[3 * u + 0] = make_float4(v1.y, -2.0f * v1.x, -2.0f * v1.y,
                               fmaf(v1.x, v1.x, v1.y * v1.y));
    T[3 * u + 1] = make_float4(v1.x - v0.x, -(v1.y - v0.y),
                               v0.x * v1.y - v0.y * v1.x, v1.x);
    T[3 * u + 2] = make_float4(v0.x, v0.y, 0.0f, 0.0f);
}

__global__ void __launch_bounds__(256, 4)
winding_kernel(const float4* __restrict__ T, int Q, int S, float invS,
               float* __restrict__ out, float* __restrict__ bmax) {
    __shared__ float s_w[4][256];
    __shared__ float s_m[4][256];
    __shared__ float s_red[4];

    const int tid  = threadIdx.x;
    const int lane = tid & 63;
    const int wid  = __builtin_amdgcn_readfirstlane(tid >> 6);

    const int pixBase = blockIdx.x * 256;    // block covers 256 pixels
    const int base    = wid * Q;             // this wave's edge range (scalar)

    // 4 pixel chains per lane: pixel = pixBase + 64*cc + lane
    float px[4], py[4];
    #pragma unroll
    for (int cc = 0; cc < 4; ++cc) {
        const int p = pixBase + 64 * cc + lane;
        const int i = p / S, j = p - i * S;
        px[cc] = (float)i * invS;
        py[cc] = (float)j * invS;
    }

    // init from vertex(base): d2' = A - 2v.p  (|p|^2 added in epilogue)
    const float4 v0 = T[3 * base];
    float dyc[4], minn[4], wcorr[4];
    int wind[4];
    #pragma unroll
    for (int cc = 0; cc < 4; ++cc) {
        dyc[cc]   = v0.x - py[cc];
        minn[cc]  = fmaf(v0.z, py[cc], fmaf(v0.y, px[cc], v0.w));
        wcorr[cc] = 0.0f;
        wind[cc]  = 0;
    }

    #pragma unroll 3
    for (int k = 1; k <= Q; ++k) {
        const float4 q0 = T[3 * (base + k) + 0];   // scalar loads
        const float4 q1 = T[3 * (base + k) + 1];

        float crzv[4], dynv[4];
        float m4 = 1e30f;
        #pragma unroll
        for (int cc = 0; cc < 4; ++cc) {
            const float U   = fmaf(q0.y, px[cc], q0.w);  // -2vx*px + A
            const float W   = fmaf(q1.y, px[cc], q1.z);  // -EY*px + C
            const float dyn = q0.x - py[cc];
            const float d2  = fmaf(q0.z, py[cc], U);     // A - 2v.p
            minn[cc] = fminf(minn[cc], d2);
            const float crz = fmaf(q1.x, py[cc], W);     // C + py*EX - px*EY
            crzv[cc] = crz; dynv[cc] = dyn;
            // half-open ray crossing (identical predicates to R8-R11)
            const bool pc = (dyc[cc] <= 0.0f);
            const bool pn = (dyn     <= 0.0f);
            const int up = (pc & !pn & (crz > 0.0f)) ? 1 : 0;
            const int dn = (!pc & pn & (crz < 0.0f)) ? 1 : 0;
            wind[cc] += up - dn;
            m4 = fminf(m4, fabsf(crz));
        }

        if (__any(m4 < CTHR)) {          // rare: exact tanh-weight correction
            const float4 q2 = T[3 * (base + k) + 2];
            #pragma unroll
            for (int cc = 0; cc < 4; ++cc) {
                const float crz = crzv[cc];
                const float dxc = q2.x - px[cc];
                const float dxn = q1.w - px[cc];
                const float dot = fmaf(dxc, dxn, dyc[cc] * dynv[cc]);
                const float ay = fabsf(crz);
                const float ax = fabsf(dot);
                const float mn = fminf(ax, ay);
                const float mx = fmaxf(ax, ay);
                const float qq = mn * __builtin_amdgcn_rcpf(fmaxf(mx, 1e-30f));
                float an = atan01(qq);
                an = (ay > ax)    ? (HPI_F - an) : an;
                an = (dot < 0.0f) ? (PI_F - an)  : an;
                const float e = __expf(ay * -KK2);
                const float t = (1.0f - e) * __builtin_amdgcn_rcpf(1.0f + e);
                // (1-t)==0 exactly for |crz|>=CTHR -> no lane mask needed
                wcorr[cc] = fmaf(1.0f - t, copysignf(an, -crz), wcorr[cc]);
            }
        }

        #pragma unroll
        for (int cc = 0; cc < 4; ++cc) dyc[cc] = dynv[cc];
    }

    #pragma unroll
    for (int cc = 0; cc < 4; ++cc) {
        const int idx = 64 * cc + lane;
        s_w[wid][idx] = fmaf(-TWO_PI, (float)wind[cc], -wcorr[cc]);
        s_m[wid][idx] = minn[cc];
    }
    __syncthreads();

    // each thread finalizes one pixel
    const float wt = (s_w[0][tid] + s_w[1][tid]) + (s_w[2][tid] + s_w[3][tid]);
    float mt = fminf(fminf(s_m[0][tid], s_m[1][tid]),
                     fminf(s_m[2][tid], s_m[3][tid]));
    const int p = pixBase + tid;
    const int i = p / S, j = p - i * S;
    const float ppx = (float)i * invS, ppy = (float)j * invS;
    mt = fmaxf(fmaf(ppx, ppx, fmaf(ppy, ppy, mt)), 0.0f);  // + |p|^2, >=0
    const float prod = (wt * INV_2PI) * __builtin_amdgcn_sqrtf(mt);
    out[p] = prod;

    float v = prod;
    #pragma unroll
    for (int off = 32; off >= 1; off >>= 1)
        v = fmaxf(v, __shfl_down(v, off, 64));
    if (lane == 0) s_red[wid] = v;
    __syncthreads();
    if (tid == 0)
        bmax[blockIdx.x] = fmaxf(fmaxf(s_red[0], s_red[1]),
                                 fmaxf(s_red[2], s_red[3]));
}

__global__ void __launch_bounds__(256)
normalize_kernel(float4* __restrict__ out4, const float* __restrict__ bmax,
                 int nmax, int total4) {
    const int tid  = threadIdx.x;
    const int lane = tid & 63;
    const int wid  = tid >> 6;

    float m = -INFINITY;
    for (int t = tid; t < nmax; t += 256) m = fmaxf(m, bmax[t]);
    #pragma unroll
    for (int off = 32; off >= 1; off >>= 1)
        m = fmaxf(m, __shfl_down(m, off, 64));
    __shared__ float sm[4];
    if (lane == 0) sm[wid] = m;
    __syncthreads();
    m = fmaxf(fmaxf(sm[0], sm[1]), fmaxf(sm[2], sm[3]));
    const float inv = 1.0f / m;

    const int idx = blockIdx.x * 256 + tid;
    if (idx < total4) {
        float4 v = out4[idx];
        v.x *= inv; v.y *= inv; v.z *= inv; v.w *= inv;
        out4[idx] = v;
    }
}

extern "C" void kernel_launch(void* const* d_in, const int* in_sizes, int n_in,
                              void* d_out, int out_size, void* d_ws, size_t ws_size,
                              hipStream_t stream) {
    const float2* contour = (const float2*)d_in[0];
    const int N = in_sizes[0] / 2;                       // 200 (<=201 padded)
    const int S = (int)(sqrt((double)out_size) + 0.5);   // 384
    const float invS = 1.0f / (float)S;
    float* out  = (float*)d_out;
    float* bmax = (float*)d_ws;                          // 576 floats
    float4* T   = (float4*)((char*)d_ws + 16384);        // 205*3 float4 table

    prep_kernel<<<1, 256, 0, stream>>>(contour, T, N);

    // 4-way split of 204 padded edges: Q=51 per wave; pads are exact no-ops
    const int Q = 51;
    const int total   = S * S;
    const int wblocks = total / 256;                     // 576 (exact)
    winding_kernel<<<wblocks, 256, 0, stream>>>(T, Q, S, invS, out, bmax);

    const int total4  = total / 4;
    const int nblocks = (total4 + 255) / 256;            // 144
    normalize_kernel<<<nblocks, 256, 0, stream>>>((float4*)out, bmax,
                                                  wblocks, total4);
}

// Round 13
// 69.206 us; speedup vs baseline: 1.2968x; 1.2336x over previous
//
#include <hip/hip_runtime.h>
#include <math.h>

// Contour-to-distance-map, round 13: scanline winding.
// 12-round model: total = C + body-cycles, C ~= 63us fixed (40us harness ws
// poison fill + ~10us graph/launch overhead + normalize + gaps); winding_R8
// ~= 12us. Only algorithmic cuts remain. Winding is piecewise-constant along
// a column: per edge the R8 up/dn indicator [py in [ylo,yhi)) * [s*V(py)>0]
// (V = EX*py + W linear in py) changes at <=2 breakpoints -> 2 difference-
// array events; 384-prefix-sum gives the whole column. 384x less winding
// work. wind(j=0)==0 exactly (all vertex y>0). tanh-correction fires only in
// the |V|<9e-5 band (|py-root|<9e-5/|EX|, ~0-1 px per edge-column; coop
// fallback for near-x-constant edges). Events/gate/correction all use the
// SAME line-form V (consistency validated by R12's identical absmax).
// Signs hand-verified: CCW square -> wind=+1, w=-2pi (ref winding -1).

#define INV_2PI 0.15915494309189535f
#define TWO_PI  6.28318530717958648f
#define PI_F    3.14159265358979323846f
#define HPI_F   1.57079632679489662f
#define KK2     200000.0f             // 2*k
#define CTHR    9e-5f                 // |V| below this -> (1-t) != 0

__device__ __forceinline__ float atan01(float q) {
    // A&S 4.4.49: atan(q), q in [0,1], |err| <= 1e-5
    const float z = q * q;
    float p = fmaf(z,  0.0208351f, -0.0851330f);
    p = fmaf(z, p,  0.1801410f);
    p = fmaf(z, p, -0.3302995f);
    p = fmaf(z, p,  0.9998660f);
    return q * p;
}

// (1-t)*copysign(an, -V) for edge (a->b), pixel (px,py), V = line-form cross
__device__ __forceinline__ float corr_term(float ax_, float ay_, float bx_,
                                           float by_, float px, float py,
                                           float V) {
    const float dxc = ax_ - px, dyc = ay_ - py;
    const float dxn = bx_ - px, dyn = by_ - py;
    const float dot = fmaf(dxc, dxn, dyc * dyn);
    const float ay = fabsf(V), ax = fabsf(dot);
    const float mn = fminf(ax, ay), mx = fmaxf(ax, ay);
    const float q  = mn * __builtin_amdgcn_rcpf(fmaxf(mx, 1e-30f));
    float an = atan01(q);
    an = (ay > ax)    ? (HPI_F - an) : an;
    an = (dot < 0.0f) ? (PI_F - an)  : an;
    const float e = __expf(ay * -KK2);
    const float t = (1.0f - e) * __builtin_amdgcn_rcpf(1.0f + e);
    return (1.0f - t) * copysignf(an, -V);
}

__global__ void __launch_bounds__(256)
scan_kernel(const float2* __restrict__ c, int N, int S, float invS,
            float* __restrict__ wbuf) {
    __shared__ int   D[512];          // difference array (slots >=S harmless)
    __shared__ float WC[512];         // correction accumulator
    __shared__ int   lst[16];
    __shared__ int   lcnt;

    const int tid = threadIdx.x;
    const int col = blockIdx.x;       // column i (x index)
    const float px = (float)col * invS;
    const float Sf = (float)S;

    for (int t = tid; t < 512; t += 256) { D[t] = 0; WC[t] = 0.0f; }
    if (tid == 0) lcnt = 0;
    __syncthreads();

    for (int n = tid; n < N; n += 256) {
        const float2 a = c[n];
        const float2 b = c[(n + 1 < N) ? (n + 1) : 0];
        const float EX = b.x - a.x;
        const float EY = b.y - a.y;
        const float Cc = a.x * b.y - a.y * b.x;
        const float W  = fmaf(-px, EY, Cc);      // V(py) = EX*py + W

        // ---- winding events: +s on j in [ylo,yhi) where s*V(py_j) > 0 ----
        const float ylo = fminf(a.y, b.y);
        const float yhi = fmaxf(a.y, b.y);
        const int s = (b.y > a.y) ? 1 : -1;
        int ja = (int)ceilf(ylo * Sf);           // py >= ylo  (half-open hi)
        int jb = (int)ceilf(yhi * Sf);
        ja = max(ja, 0); jb = min(jb, S);
        if (ja < jb) {
            const float Ga = (float)s * fmaf(EX, (float)ja * invS, W);
            const float Gb = (float)s * fmaf(EX, (float)(jb - 1) * invS, W);
            int j0 = ja, j1 = jb;
            if (Ga > 0.0f && Gb > 0.0f) {
                // full range
            } else if (!(Ga > 0.0f) && !(Gb > 0.0f)) {
                j1 = j0;                         // empty
            } else {
                const float r = -W / EX;         // EX != 0 (signs differ)
                const float rj = fminf(fmaxf(r * Sf, -1.0f), 386.0f);
                int jm = (int)ceilf(rj);
                jm = min(max(jm, ja), jb);
                if (Ga > 0.0f) j1 = jm; else j0 = jm;
            }
            if (j0 < j1) {
                atomicAdd(&D[j0],  s);
                atomicAdd(&D[j1], -s);
            }
        }

        // ---- correction band: j with |V(py_j)| < CTHR ----
        const float aEX = fabsf(EX);
        if (aEX < 1e-12f) {
            if (fabsf(W) < CTHR) {
                const int k = atomicAdd(&lcnt, 1);
                if (k < 16) lst[k] = n;
            }
        } else {
            const float r  = -W / EX;
            const float dl = CTHR / aEX;
            float flo = (r - dl) * Sf;
            float fhi = (r + dl) * Sf;
            if (fhi >= 0.0f && flo <= Sf - 1.0f) {
                flo = fmaxf(flo, 0.0f);
                fhi = fminf(fhi, Sf - 1.0f);
                const int jl = (int)ceilf(flo);
                const int jh = (int)floorf(fhi);
                if (jh - jl > 12) {
                    const int k = atomicAdd(&lcnt, 1);
                    if (k < 16) lst[k] = n;
                } else {
                    for (int j = jl; j <= jh; ++j) {
                        const float py = (float)j * invS;
                        const float V = fmaf(EX, py, W);
                        if (fabsf(V) < CTHR)
                            atomicAdd(&WC[j],
                                      corr_term(a.x, a.y, b.x, b.y, px, py, V));
                    }
                }
            }
        }
    }
    __syncthreads();

    // ---- cooperative corrections for wide-band edges (rare) ----
    const int L = min(lcnt, 16);
    for (int k = 0; k < L; ++k) {
        const int n = lst[k];
        const float2 a = c[n];
        const float2 b = c[(n + 1 < N) ? (n + 1) : 0];
        const float EX = b.x - a.x;
        const float EY = b.y - a.y;
        const float W  = fmaf(-px, EY, a.x * b.y - a.y * b.x);
        for (int j = tid; j < S; j += 256) {
            const float py = (float)j * invS;
            const float V = fmaf(EX, py, W);
            if (fabsf(V) < CTHR)
                atomicAdd(&WC[j], corr_term(a.x, a.y, b.x, b.y, px, py, V));
        }
    }
    __syncthreads();

    // ---- inclusive prefix sum of D over 512 slots (Hillis-Steele) ----
    #pragma unroll
    for (int off = 1; off < 512; off <<= 1) {
        const int j0 = tid, j1 = tid + 256;
        const int v0 = D[j0] + ((j0 >= off) ? D[j0 - off] : 0);
        const int v1 = D[j1] + ((j1 >= off) ? D[j1 - off] : 0);
        __syncthreads();
        D[j0] = v0; D[j1] = v1;
        __syncthreads();
    }

    // ---- w(j) = -2*pi*wind(j) - WC(j) ----
    for (int j = tid; j < S; j += 256)
        wbuf[col * S + j] = fmaf(-TWO_PI, (float)D[j], -WC[j]);
}

__global__ void __launch_bounds__(256)
prod_kernel(const float2* __restrict__ c, int N, int S, float invS,
            const float* __restrict__ wbuf, float* __restrict__ out,
            float* __restrict__ bmax) {
    const int tid = threadIdx.x;
    const int lane = tid & 63;
    const int wid  = tid >> 6;
    const int p = blockIdx.x * 256 + tid;          // 147456 = 576*256 exact
    const int i = p / S, j = p - i * S;
    const float px = (float)i * invS, py = (float)j * invS;

    float m0 = 1e30f, m1 = 1e30f, m2 = 1e30f, m3 = 1e30f;
    int n = 0;
    for (; n + 4 <= N; n += 4) {                   // uniform n -> scalar loads
        const float2 v0 = c[n],     v1 = c[n + 1];
        const float2 v2 = c[n + 2], v3 = c[n + 3];
        float dx, dy;
        dx = v0.x - px; dy = v0.y - py; m0 = fminf(m0, fmaf(dx, dx, dy * dy));
        dx = v1.x - px; dy = v1.y - py; m1 = fminf(m1, fmaf(dx, dx, dy * dy));
        dx = v2.x - px; dy = v2.y - py; m2 = fminf(m2, fmaf(dx, dx, dy * dy));
        dx = v3.x - px; dy = v3.y - py; m3 = fminf(m3, fmaf(dx, dx, dy * dy));
    }
    for (; n < N; ++n) {
        const float2 v = c[n];
        const float dx = v.x - px, dy = v.y - py;
        m0 = fminf(m0, fmaf(dx, dx, dy * dy));
    }
    const float minn = fminf(fminf(m0, m1), fminf(m2, m3));
    const float prod = (wbuf[p] * INV_2PI) * __builtin_amdgcn_sqrtf(minn);
    out[p] = prod;

    float v = prod;
    #pragma unroll
    for (int off = 32; off >= 1; off >>= 1)
        v = fmaxf(v, __shfl_down(v, off, 64));
    __shared__ float s_red[4];
    if (lane == 0) s_red[wid] = v;
    __syncthreads();
    if (tid == 0)
        bmax[blockIdx.x] = fmaxf(fmaxf(s_red[0], s_red[1]),
                                 fmaxf(s_red[2], s_red[3]));
}

__global__ void __launch_bounds__(256)
normalize_kernel(float4* __restrict__ out4, const float* __restrict__ bmax,
                 int nmax, int total4) {
    const int tid  = threadIdx.x;
    const int lane = tid & 63;
    const int wid  = tid >> 6;

    float m = -INFINITY;
    for (int t = tid; t < nmax; t += 256) m = fmaxf(m, bmax[t]);
    #pragma unroll
    for (int off = 32; off >= 1; off >>= 1)
        m = fmaxf(m, __shfl_down(m, off, 64));
    __shared__ float sm[4];
    if (lane == 0) sm[wid] = m;
    __syncthreads();
    m = fmaxf(fmaxf(sm[0], sm[1]), fmaxf(sm[2], sm[3]));
    const float inv = 1.0f / m;

    const int idx = blockIdx.x * 256 + tid;
    if (idx < total4) {
        float4 v = out4[idx];
        v.x *= inv; v.y *= inv; v.z *= inv; v.w *= inv;
        out4[idx] = v;
    }
}

extern "C" void kernel_launch(void* const* d_in, const int* in_sizes, int n_in,
                              void* d_out, int out_size, void* d_ws, size_t ws_size,
                              hipStream_t stream) {
    const float2* contour = (const float2*)d_in[0];
    const int N = in_sizes[0] / 2;                       // 200
    const int S = (int)(sqrt((double)out_size) + 0.5);   // 384
    const float invS = 1.0f / (float)S;
    float* out  = (float*)d_out;
    float* bmax = (float*)d_ws;                          // 576 floats
    float* wbuf = (float*)((char*)d_ws + 16384);         // S*S winding grid

    scan_kernel<<<S, 256, 0, stream>>>(contour, N, S, invS, wbuf);

    const int total  = S * S;
    const int pblocks = total / 256;                     // 576 (exact)
    prod_kernel<<<pblocks, 256, 0, stream>>>(contour, N, S, invS, wbuf,
                                             out, bmax);

    const int total4  = total / 4;
    const int nblocks = (total4 + 255) / 256;            // 144
    normalize_kernel<<<nblocks, 256, 0, stream>>>((float4*)out, bmax,
                                                  pblocks, total4);
}

// Round 14
// 64.332 us; speedup vs baseline: 1.3950x; 1.0758x over previous
//
#include <hip/hip_runtime.h>
#include <math.h>

// Contour-to-distance-map, round 14.
// R13 attribution (zero-gap model, validated by R1: 40+100.8+2.6=143.5):
// scan+prod = 26.6us, and scan is ~1-2us by op count -> prod (min-dist,
// still full O(S^2*N)=29.5M evals) ~= 20us. Fix: tile-pruned min-distance.
// Block = 16x16 pixel tile; triangle inequality: v can be nearest for a
// tile pixel only if dist(center,v) <= sqrt(minc)+2r (r=0.0276 half-diag;
// margin used 0.0560 > exact 0.05524). ~6 candidates vs 200 for uniform
// vertices. Per-pixel min uses bit-identical fmaf over a superset of the
// argmin -> minn EXACT. Winding (scan) and normalize unchanged from R13.

#define INV_2PI 0.15915494309189535f
#define TWO_PI  6.28318530717958648f
#define PI_F    3.14159265358979323846f
#define HPI_F   1.57079632679489662f
#define KK2     200000.0f             // 2*k
#define CTHR    9e-5f                 // |V| below this -> (1-t) != 0

__device__ __forceinline__ float atan01(float q) {
    // A&S 4.4.49: atan(q), q in [0,1], |err| <= 1e-5
    const float z = q * q;
    float p = fmaf(z,  0.0208351f, -0.0851330f);
    p = fmaf(z, p,  0.1801410f);
    p = fmaf(z, p, -0.3302995f);
    p = fmaf(z, p,  0.9998660f);
    return q * p;
}

// (1-t)*copysign(an, -V) for edge (a->b), pixel (px,py), V = line-form cross
__device__ __forceinline__ float corr_term(float ax_, float ay_, float bx_,
                                           float by_, float px, float py,
                                           float V) {
    const float dxc = ax_ - px, dyc = ay_ - py;
    const float dxn = bx_ - px, dyn = by_ - py;
    const float dot = fmaf(dxc, dxn, dyc * dyn);
    const float ay = fabsf(V), ax = fabsf(dot);
    const float mn = fminf(ax, ay), mx = fmaxf(ax, ay);
    const float q  = mn * __builtin_amdgcn_rcpf(fmaxf(mx, 1e-30f));
    float an = atan01(q);
    an = (ay > ax)    ? (HPI_F - an) : an;
    an = (dot < 0.0f) ? (PI_F - an)  : an;
    const float e = __expf(ay * -KK2);
    const float t = (1.0f - e) * __builtin_amdgcn_rcpf(1.0f + e);
    return (1.0f - t) * copysignf(an, -V);
}

__global__ void __launch_bounds__(256)
scan_kernel(const float2* __restrict__ c, int N, int S, float invS,
            float* __restrict__ wbuf) {
    __shared__ int   D[512];          // difference array (slots >=S harmless)
    __shared__ float WC[512];         // correction accumulator
    __shared__ int   lst[16];
    __shared__ int   lcnt;

    const int tid = threadIdx.x;
    const int col = blockIdx.x;       // column i (x index)
    const float px = (float)col * invS;
    const float Sf = (float)S;

    for (int t = tid; t < 512; t += 256) { D[t] = 0; WC[t] = 0.0f; }
    if (tid == 0) lcnt = 0;
    __syncthreads();

    for (int n = tid; n < N; n += 256) {
        const float2 a = c[n];
        const float2 b = c[(n + 1 < N) ? (n + 1) : 0];
        const float EX = b.x - a.x;
        const float EY = b.y - a.y;
        const float Cc = a.x * b.y - a.y * b.x;
        const float W  = fmaf(-px, EY, Cc);      // V(py) = EX*py + W

        // ---- winding events: +s on j in [ylo,yhi) where s*V(py_j) > 0 ----
        const float ylo = fminf(a.y, b.y);
        const float yhi = fmaxf(a.y, b.y);
        const int s = (b.y > a.y) ? 1 : -1;
        int ja = (int)ceilf(ylo * Sf);           // py >= ylo  (half-open hi)
        int jb = (int)ceilf(yhi * Sf);
        ja = max(ja, 0); jb = min(jb, S);
        if (ja < jb) {
            const float Ga = (float)s * fmaf(EX, (float)ja * invS, W);
            const float Gb = (float)s * fmaf(EX, (float)(jb - 1) * invS, W);
            int j0 = ja, j1 = jb;
            if (Ga > 0.0f && Gb > 0.0f) {
                // full range
            } else if (!(Ga > 0.0f) && !(Gb > 0.0f)) {
                j1 = j0;                         // empty
            } else {
                const float r = -W / EX;         // EX != 0 (signs differ)
                const float rj = fminf(fmaxf(r * Sf, -1.0f), 386.0f);
                int jm = (int)ceilf(rj);
                jm = min(max(jm, ja), jb);
                if (Ga > 0.0f) j1 = jm; else j0 = jm;
            }
            if (j0 < j1) {
                atomicAdd(&D[j0],  s);
                atomicAdd(&D[j1], -s);
            }
        }

        // ---- correction band: j with |V(py_j)| < CTHR ----
        const float aEX = fabsf(EX);
        if (aEX < 1e-12f) {
            if (fabsf(W) < CTHR) {
                const int k = atomicAdd(&lcnt, 1);
                if (k < 16) lst[k] = n;
            }
        } else {
            const float r  = -W / EX;
            const float dl = CTHR / aEX;
            float flo = (r - dl) * Sf;
            float fhi = (r + dl) * Sf;
            if (fhi >= 0.0f && flo <= Sf - 1.0f) {
                flo = fmaxf(flo, 0.0f);
                fhi = fminf(fhi, Sf - 1.0f);
                const int jl = (int)ceilf(flo);
                const int jh = (int)floorf(fhi);
                if (jh - jl > 12) {
                    const int k = atomicAdd(&lcnt, 1);
                    if (k < 16) lst[k] = n;
                } else {
                    for (int j = jl; j <= jh; ++j) {
                        const float py = (float)j * invS;
                        const float V = fmaf(EX, py, W);
                        if (fabsf(V) < CTHR)
                            atomicAdd(&WC[j],
                                      corr_term(a.x, a.y, b.x, b.y, px, py, V));
                    }
                }
            }
        }
    }
    __syncthreads();

    // ---- cooperative corrections for wide-band edges (rare) ----
    const int L = min(lcnt, 16);
    for (int k = 0; k < L; ++k) {
        const int n = lst[k];
        const float2 a = c[n];
        const float2 b = c[(n + 1 < N) ? (n + 1) : 0];
        const float EX = b.x - a.x;
        const float EY = b.y - a.y;
        const float W  = fmaf(-px, EY, a.x * b.y - a.y * b.x);
        for (int j = tid; j < S; j += 256) {
            const float py = (float)j * invS;
            const float V = fmaf(EX, py, W);
            if (fabsf(V) < CTHR)
                atomicAdd(&WC[j], corr_term(a.x, a.y, b.x, b.y, px, py, V));
        }
    }
    __syncthreads();

    // ---- inclusive prefix sum of D over 512 slots (Hillis-Steele) ----
    #pragma unroll
    for (int off = 1; off < 512; off <<= 1) {
        const int j0 = tid, j1 = tid + 256;
        const int v0 = D[j0] + ((j0 >= off) ? D[j0 - off] : 0);
        const int v1 = D[j1] + ((j1 >= off) ? D[j1 - off] : 0);
        __syncthreads();
        D[j0] = v0; D[j1] = v1;
        __syncthreads();
    }

    // ---- w(j) = -2*pi*wind(j) - WC(j) ----
    for (int j = tid; j < S; j += 256)
        wbuf[col * S + j] = fmaf(-TWO_PI, (float)D[j], -WC[j]);
}

__global__ void __launch_bounds__(256)
prod_kernel(const float2* __restrict__ c, int N, int S, float invS,
            const float* __restrict__ wbuf, float* __restrict__ out,
            float* __restrict__ bmax) {
    __shared__ float2 sv[256];        // candidate vertices (cap N<=256)
    __shared__ int    scnt;
    __shared__ float  s_cd[4];
    __shared__ float  s_red[4];

    const int tid  = threadIdx.x;
    const int lane = tid & 63;
    const int wid  = tid >> 6;

    // 16x16 pixel tile; S/16 tiles per dim (384/16 = 24)
    const int nbx = S >> 4;
    const int bi = blockIdx.x / nbx;
    const int bj = blockIdx.x - bi * nbx;
    const int i = (bi << 4) + (tid >> 4);
    const int j = (bj << 4) + (tid & 15);
    const float px = (float)i * invS, py = (float)j * invS;

    // tile center
    const float cx = ((float)(bi << 4) + 7.5f) * invS;
    const float cy = ((float)(bj << 4) + 7.5f) * invS;

    // pass 1: min center-distance^2 over all vertices
    float cmin = 1e30f;
    for (int n = tid; n < N; n += 256) {
        const float2 v = c[n];
        const float dx = v.x - cx, dy = v.y - cy;
        cmin = fminf(cmin, fmaf(dx, dx, dy * dy));
    }
    #pragma unroll
    for (int off = 32; off >= 1; off >>= 1)
        cmin = fminf(cmin, __shfl_down(cmin, off, 64));
    if (lane == 0) s_cd[wid] = cmin;
    if (tid == 0) scnt = 0;
    __syncthreads();
    const float minc = fminf(fminf(s_cd[0], s_cd[1]), fminf(s_cd[2], s_cd[3]));

    // candidate threshold: dist(center,v) <= sqrt(minc) + 2r, 2r=0.0560
    // (exact 2r = 2*sqrt(2)*7.5/384 = 0.05524; inflated for fp safety)
    const float T  = sqrtf(minc) + 0.0560f;
    const float T2 = T * T;

    // pass 2: append candidates
    for (int n = tid; n < N; n += 256) {
        const float2 v = c[n];
        const float dx = v.x - cx, dy = v.y - cy;
        if (fmaf(dx, dx, dy * dy) <= T2) {
            const int k = atomicAdd(&scnt, 1);
            sv[k] = v;
        }
    }
    __syncthreads();

    // per-pixel min over candidates (LDS broadcast reads; superset of the
    // argmin with bit-identical fmaf -> minn exact)
    const int M = scnt;
    float minn = 1e30f;
    for (int k = 0; k < M; ++k) {
        const float2 v = sv[k];
        const float dx = v.x - px, dy = v.y - py;
        minn = fminf(minn, fmaf(dx, dx, dy * dy));
    }

    const int p = i * S + j;
    const float prod = (wbuf[p] * INV_2PI) * __builtin_amdgcn_sqrtf(minn);
    out[p] = prod;

    float v = prod;
    #pragma unroll
    for (int off = 32; off >= 1; off >>= 1)
        v = fmaxf(v, __shfl_down(v, off, 64));
    if (lane == 0) s_red[wid] = v;
    __syncthreads();
    if (tid == 0)
        bmax[blockIdx.x] = fmaxf(fmaxf(s_red[0], s_red[1]),
                                 fmaxf(s_red[2], s_red[3]));
}

__global__ void __launch_bounds__(256)
normalize_kernel(float4* __restrict__ out4, const float* __restrict__ bmax,
                 int nmax, int total4) {
    const int tid  = threadIdx.x;
    const int lane = tid & 63;
    const int wid  = tid >> 6;

    float m = -INFINITY;
    for (int t = tid; t < nmax; t += 256) m = fmaxf(m, bmax[t]);
    #pragma unroll
    for (int off = 32; off >= 1; off >>= 1)
        m = fmaxf(m, __shfl_down(m, off, 64));
    __shared__ float sm[4];
    if (lane == 0) sm[wid] = m;
    __syncthreads();
    m = fmaxf(fmaxf(sm[0], sm[1]), fmaxf(sm[2], sm[3]));
    const float inv = 1.0f / m;

    const int idx = blockIdx.x * 256 + tid;
    if (idx < total4) {
        float4 v = out4[idx];
        v.x *= inv; v.y *= inv; v.z *= inv; v.w *= inv;
        out4[idx] = v;
    }
}

extern "C" void kernel_launch(void* const* d_in, const int* in_sizes, int n_in,
                              void* d_out, int out_size, void* d_ws, size_t ws_size,
                              hipStream_t stream) {
    const float2* contour = (const float2*)d_in[0];
    const int N = in_sizes[0] / 2;                       // 200 (<=256)
    const int S = (int)(sqrt((double)out_size) + 0.5);   // 384
    const float invS = 1.0f / (float)S;
    float* out  = (float*)d_out;
    float* bmax = (float*)d_ws;                          // 576 floats
    float* wbuf = (float*)((char*)d_ws + 16384);         // S*S winding grid

    scan_kernel<<<S, 256, 0, stream>>>(contour, N, S, invS, wbuf);

    const int total  = S * S;
    const int pblocks = total / 256;                     // 576 (exact)
    prod_kernel<<<pblocks, 256, 0, stream>>>(contour, N, S, invS, wbuf,
                                             out, bmax);

    const int total4  = total / 4;
    const int nblocks = (total4 + 255) / 256;            // 144
    normalize_kernel<<<nblocks, 256, 0, stream>>>((float4*)out, bmax,
                                                  pblocks, total4);
}